// Round 10
// baseline (132.819 us; speedup 1.0000x reference)
//
#include <hip/hip_runtime.h>

#define NB 4
#define TT 512          // TQ = TP
#define DD 256
#define K2L2E    2.885390081777927f     // 2*log2(e): e^{2x} = 2^{K*x}
#define NEG2L2E (-2.885390081777927f)

#if defined(__has_builtin)
# if __has_builtin(__builtin_amdgcn_global_load_lds)
#  define HAS_GLL 1
# endif
#endif

typedef float v2f __attribute__((ext_vector_type(2)));

__device__ __forceinline__ v2f pk_fma(v2f a, v2f b, v2f c) {
#if defined(__has_builtin)
# if __has_builtin(__builtin_elementwise_fma)
    return __builtin_elementwise_fma(a, b, c);
# else
    v2f r; r.x = __builtin_fmaf(a.x, b.x, c.x); r.y = __builtin_fmaf(a.y, b.y, c.y); return r;
# endif
#else
    v2f r; r.x = __builtin_fmaf(a.x, b.x, c.x); r.y = __builtin_fmaf(a.y, b.y, c.y); return r;
#endif
}
__device__ __forceinline__ v2f splat2(float s) { v2f r; r.x = s; r.y = s; return r; }

__device__ __forceinline__ void stage16(const float* __restrict__ g, float* l) {
#ifdef HAS_GLL
    __builtin_amdgcn_global_load_lds((const __attribute__((address_space(1))) void*)g,
                                     (__attribute__((address_space(3))) void*)l, 16, 0, 0);
#else
    *(float4*)l = *(const float4*)g;
#endif
}

// ============ P1: projections + exp epilogue ============
// expQ[b][d][q] = e^{2*(q@W0)[q,d]}  (TRANSPOSED, q-minor)
// expP[b][p][d] = e^{2*(p@W1)[p,d]}  (NATURAL, d-minor)
__global__ __launch_bounds__(256) void proj_exp_kernel(
    const float* __restrict__ qin, const float* __restrict__ pin,
    const float* __restrict__ W0, const float* __restrict__ W1,
    float* __restrict__ expQ, float* __restrict__ expP)
{
    const int blk = blockIdx.x;
    const int wh = blk >> 8, tid = blk & 255;
    const int m0 = (tid >> 2) * 32, n0 = (tid & 3) * 64;
    const float* A = wh ? pin : qin;
    const float* W = wh ? W1 : W0;

    __shared__ __align__(16) float As[32 * 34];   // [k][m]
    __shared__ __align__(16) float Bs[32 * 64];   // [k][n]

    const int t  = threadIdx.x;
    const int ar = t >> 3, ac4 = (t & 7) * 4;
    const int br = t >> 4, bc4 = (t & 15) * 4;
    const int tm = wh ? (t >> 4) : (t & 15);
    const int tn = wh ? (t & 15) : (t >> 4);

    const float* Ap = A + (long)(m0 + ar) * DD + ac4;

    float4 av  = *(const float4*)Ap;
    float4 bv0 = *(const float4*)(W + (long)br * DD + n0 + bc4);
    float4 bv1 = *(const float4*)(W + (long)(br + 16) * DD + n0 + bc4);

    v2f accv[2][2];
    accv[0][0] = splat2(0.f); accv[0][1] = splat2(0.f);
    accv[1][0] = splat2(0.f); accv[1][1] = splat2(0.f);

    for (int c = 0; c < 8; ++c) {
        As[(ac4 + 0) * 34 + ar] = av.x;
        As[(ac4 + 1) * 34 + ar] = av.y;
        As[(ac4 + 2) * 34 + ar] = av.z;
        As[(ac4 + 3) * 34 + ar] = av.w;
        *(float4*)&Bs[br * 64 + bc4]        = bv0;
        *(float4*)&Bs[(br + 16) * 64 + bc4] = bv1;
        __syncthreads();
        if (c < 7) {
            int k1 = (c + 1) * 32;
            av  = *(const float4*)(Ap + k1);
            bv0 = *(const float4*)(W + (long)(k1 + br) * DD + n0 + bc4);
            bv1 = *(const float4*)(W + (long)(k1 + 16 + br) * DD + n0 + bc4);
        }
        #pragma unroll
        for (int kk = 0; kk < 32; ++kk) {
            float2 a = *(const float2*)&As[kk * 34 + 2 * tm];
            float4 b = *(const float4*)&Bs[kk * 64 + 4 * tn];
            v2f b01; b01.x = b.x; b01.y = b.y;
            v2f b23; b23.x = b.z; b23.y = b.w;
            accv[0][0] = pk_fma(splat2(a.x), b01, accv[0][0]);
            accv[0][1] = pk_fma(splat2(a.x), b23, accv[0][1]);
            accv[1][0] = pk_fma(splat2(a.y), b01, accv[1][0]);
            accv[1][1] = pk_fma(splat2(a.y), b23, accv[1][1]);
        }
        __syncthreads();
    }

    float acc[2][4];
    #pragma unroll
    for (int i = 0; i < 2; ++i) {
        acc[i][0] = accv[i][0].x; acc[i][1] = accv[i][0].y;
        acc[i][2] = accv[i][1].x; acc[i][3] = accv[i][1].y;
    }

    const int bi = m0 >> 9;
    const int ml = m0 & 511;
    if (wh) {
        #pragma unroll
        for (int i = 0; i < 2; ++i) {
            float4 st;
            st.x = __builtin_amdgcn_exp2f(acc[i][0] * K2L2E);
            st.y = __builtin_amdgcn_exp2f(acc[i][1] * K2L2E);
            st.z = __builtin_amdgcn_exp2f(acc[i][2] * K2L2E);
            st.w = __builtin_amdgcn_exp2f(acc[i][3] * K2L2E);
            *(float4*)(expP + ((long)bi * TT + ml + 2 * tm + i) * DD + n0 + 4 * tn) = st;
        }
    } else {
        #pragma unroll
        for (int j = 0; j < 4; ++j) {
            int d = n0 + 4 * tn + j;
            float2 st;
            st.x = __builtin_amdgcn_exp2f(acc[0][j] * K2L2E);
            st.y = __builtin_amdgcn_exp2f(acc[1][j] * K2L2E);
            *(float2*)(expQ + ((long)bi * DD + d) * TT + ml + 2 * tm) = st;
        }
    }
}

// ============ P2: scores ============ (unchanged from R8)
__global__ __launch_bounds__(512, 6) void score_kernel(
    const float* __restrict__ expP, const float* __restrict__ expQ,
    const float* __restrict__ vc, float* __restrict__ ebuf, float* __restrict__ lpart)
{
    const int b = blockIdx.z, pt = blockIdx.y, qt = blockIdx.x;
    const int p0 = pt * 32, q0 = qt * 64;
    const int t  = threadIdx.x;
    const int qx = t & 31, py = t >> 5;

    __shared__ __align__(16) float PA[32 * 128];   // [p][d-chunk] 16 KB
    __shared__ __align__(16) float QB[128 * 64];   // [d][q] 32 KB
    __shared__ __align__(16) float vcs[DD];

    const float* gP = expP + ((long)b * TT + p0) * DD;
    const float* gQ = expQ + (long)b * DD * TT + q0;

    #pragma unroll
    for (int s = 0; s < 2; ++s) {
        int f = t + 512 * s, pr = f >> 5, d4 = (f & 31) * 4;
        stage16(gP + (long)pr * DD + d4, &PA[f * 4]);
    }
    #pragma unroll
    for (int s = 0; s < 4; ++s) {
        int f = t + 512 * s, d = f >> 4, o4 = (f & 15) * 4;
        stage16(gQ + (long)d * TT + o4, &QB[f * 4]);
    }
    if (t < DD) vcs[t] = vc[t];
    __syncthreads();

    v2f acc[2]; acc[0] = splat2(0.f); acc[1] = splat2(0.f);
    const v2f one = splat2(1.0f);

    for (int c = 0; c < 2; ++c) {
        if (c == 1) {
            __syncthreads();
            #pragma unroll
            for (int s = 0; s < 2; ++s) {
                int f = t + 512 * s, pr = f >> 5, d4 = (f & 31) * 4;
                stage16(gP + (long)pr * DD + 128 + d4, &PA[f * 4]);
            }
            #pragma unroll
            for (int s = 0; s < 4; ++s) {
                int f = t + 512 * s, d = f >> 4, o4 = (f & 15) * 4;
                stage16(gQ + (long)(128 + d) * TT + o4, &QB[f * 4]);
            }
            __syncthreads();
        }
        const float* vcb = &vcs[c * 128];
        #pragma unroll 4
        for (int dq = 0; dq < 32; ++dq) {
            float4 vq = *(const float4*)&vcb[4 * dq];
            float4 aq0 = *(const float4*)&PA[(2 * py) * 128 + 4 * dq];
            float4 aq1 = *(const float4*)&PA[(2 * py + 1) * 128 + 4 * dq];
            v2f B0 = *(const v2f*)&QB[(4 * dq + 0) * 64 + 2 * qx];
            v2f B1 = *(const v2f*)&QB[(4 * dq + 1) * 64 + 2 * qx];
            v2f B2 = *(const v2f*)&QB[(4 * dq + 2) * 64 + 2 * qx];
            v2f B3 = *(const v2f*)&QB[(4 * dq + 3) * 64 + 2 * qx];
            #pragma unroll
            for (int i = 0; i < 2; ++i) {
                float4 a = i ? aq1 : aq0;
                v2f f0 = pk_fma(splat2(a.x), B0, one);
                v2f f1 = pk_fma(splat2(a.y), B1, one);
                v2f f2 = pk_fma(splat2(a.z), B2, one);
                v2f f3 = pk_fma(splat2(a.w), B3, one);
                v2f t01 = f0 * f1;
                v2f t23 = f2 * f3;
                v2f den = t01 * t23;
                v2f n01 = pk_fma(splat2(vq.x), f1, splat2(vq.y) * f0);
                v2f n23 = pk_fma(splat2(vq.z), f3, splat2(vq.w) * f2);
                v2f num = pk_fma(n01, t23, n23 * t01);
                v2f r;
                r.x = __builtin_amdgcn_rcpf(den.x);
                r.y = __builtin_amdgcn_rcpf(den.y);
                acc[i] = pk_fma(num, r, acc[i]);
            }
        }
    }

    float* eb = ebuf + ((long)b * TT + p0) * TT + q0;
    v2f colp = splat2(0.f);
    #pragma unroll
    for (int i = 0; i < 2; ++i) {
        float2 ev;
        ev.x = __builtin_amdgcn_exp2f(acc[i].x * NEG2L2E);
        ev.y = __builtin_amdgcn_exp2f(acc[i].y * NEG2L2E);
        *(float2*)(eb + (long)(2 * py + i) * TT + 2 * qx) = ev;
        colp.x += ev.x; colp.y += ev.y;
    }
    __syncthreads();
    float* scr = (float*)&PA[0];
    *(float2*)&scr[py * 64 + 2 * qx] = make_float2(colp.x, colp.y);
    __syncthreads();
    if (t < 64) {
        float s = 0.f;
        #pragma unroll
        for (int r = 0; r < 16; ++r) s += scr[r * 64 + t];
        lpart[((long)b * 16 + pt) * TT + q0 + t] = s;
    }
}

// ============ P3: out[b,p,:] = sum_q (e[p,q]/l[q]) * qin[b,q,:] ============
// 32p x 32d tile, 512 thr (8 waves). One wave spans the tile (4p x 4d per
// lane); 8-way k-split over 128-k chunks (4 chunks -> 9 barriers); cross-wave
// LDS reduce at end. smem sized for BOTH staging (8320 f) and reduce (9216 f)
// -- R9's bug was sizing it for staging only (reduce overflowed into linv).
__global__ __launch_bounds__(512, 4) void out_kernel(
    const float* __restrict__ ebuf, const float* __restrict__ qin,
    const float* __restrict__ lpart, float* __restrict__ out)
{
    const int b = blockIdx.z, pt = blockIdx.y, dt = blockIdx.x;
    const int m0 = pt * 32, n0 = dt * 32;
    const int t    = threadIdx.x;       // 0..511
    const int wv   = t >> 6;            // wave 0..7
    const int lane = t & 63;
    const int pg   = lane >> 3;         // p = 4*pg + i (0..7)
    const int dg   = lane & 7;          // d = 4*dg + j (0..7)

    // max(staging 128*33+128*32 = 8320, reduce 8*32*36 = 9216) = 9216 floats
    __shared__ __align__(16) float smem[8 * 32 * 36];
    __shared__ float linv[TT];
    float* As = smem;                    // [128k][33] transposed, linv-scaled
    float* Bs = smem + 128 * 33;         // [128k][32d]

    {
        int qq = t;
        float sum = 0.f;
        #pragma unroll
        for (int pb = 0; pb < 16; ++pb) sum += lpart[((long)b * 16 + pb) * TT + qq];
        linv[qq] = __builtin_amdgcn_rcpf(sum);
    }
    __syncthreads();

    const float* Ab = ebuf + ((long)b * TT + m0) * TT;   // 32 p-rows x 512 k
    const float* Bb = qin + (long)b * TT * DD + n0;      // 512 k-rows x 32 d

    const int ar  = t >> 4;             // A stage: p row 0..31
    const int ak4 = (t & 15) * 4;       // A k sub-offset (0..60); plus +64

    v2f acc[4][2];
    #pragma unroll
    for (int i = 0; i < 4; ++i) { acc[i][0] = splat2(0.f); acc[i][1] = splat2(0.f); }

    for (int c = 0; c < 4; ++c) {
        const int k0 = c * 128;
        // stage B async: 4096 f = 2 f4/thread, layout [k][32d]
        #pragma unroll
        for (int s = 0; s < 2; ++s) {
            int f = t + 512 * s, kr = f >> 3, d4 = (f & 7) * 4;
            stage16(Bb + (long)(k0 + kr) * DD + d4, &Bs[f * 4]);
        }
        // stage A manual: read [p][k4] b128, scale by linv, transpose-write [k][p]
        #pragma unroll
        for (int s = 0; s < 2; ++s) {
            int kq = ak4 + 64 * s;
            float4 a  = *(const float4*)(Ab + (long)ar * TT + k0 + kq);
            float4 lv = *(const float4*)&linv[k0 + kq];
            As[(kq + 0) * 33 + ar] = a.x * lv.x;
            As[(kq + 1) * 33 + ar] = a.y * lv.y;
            As[(kq + 2) * 33 + ar] = a.z * lv.z;
            As[(kq + 3) * 33 + ar] = a.w * lv.w;
        }
        __syncthreads();
        // wave wv computes kk in [16wv, 16wv+16)
        const int kb = 16 * wv;
        #pragma unroll
        for (int u = 0; u < 16; ++u) {
            int kk = kb + u;
            float4 a  = *(const float4*)&As[kk * 33 + 4 * pg];
            float4 bq = *(const float4*)&Bs[kk * 32 + 4 * dg];
            v2f b0; b0.x = bq.x; b0.y = bq.y;
            v2f b1; b1.x = bq.z; b1.y = bq.w;
            acc[0][0] = pk_fma(splat2(a.x), b0, acc[0][0]);
            acc[0][1] = pk_fma(splat2(a.x), b1, acc[0][1]);
            acc[1][0] = pk_fma(splat2(a.y), b0, acc[1][0]);
            acc[1][1] = pk_fma(splat2(a.y), b1, acc[1][1]);
            acc[2][0] = pk_fma(splat2(a.z), b0, acc[2][0]);
            acc[2][1] = pk_fma(splat2(a.z), b1, acc[2][1]);
            acc[3][0] = pk_fma(splat2(a.w), b0, acc[3][0]);
            acc[3][1] = pk_fma(splat2(a.w), b1, acc[3][1]);
        }
        __syncthreads();
    }

    // cross-wave k reduction: scratch [wv][32p][36] = 9216 floats (fits now)
    float* scr = smem;
    #pragma unroll
    for (int i = 0; i < 4; ++i) {
        *(v2f*)&scr[wv * 1152 + (4 * pg + i) * 36 + 4 * dg]     = acc[i][0];
        *(v2f*)&scr[wv * 1152 + (4 * pg + i) * 36 + 4 * dg + 2] = acc[i][1];
    }
    __syncthreads();
    {
        int pr = t >> 4, d2 = (t & 15) * 2;     // 32p x 16 d-pairs
        v2f s = splat2(0.f);
        #pragma unroll
        for (int w = 0; w < 8; ++w) {
            v2f v = *(const v2f*)&scr[w * 1152 + pr * 36 + d2];
            s += v;
        }
        *(float2*)(out + ((long)b * TT + m0 + pr) * DD + n0 + d2) = make_float2(s.x, s.y);
    }
}

extern "C" void kernel_launch(void* const* d_in, const int* in_sizes, int n_in,
                              void* d_out, int out_size, void* d_ws, size_t ws_size,
                              hipStream_t stream) {
    const float* q  = (const float*)d_in[0];
    const float* p  = (const float*)d_in[1];
    const float* W0 = (const float*)d_in[2];
    const float* W1 = (const float*)d_in[3];
    const float* vc = (const float*)d_in[4];
    float* out = (float*)d_out;

    float* ws    = (float*)d_ws;
    float* expQ  = ws;                // [4][256][512]  e^{2*projQ}, [b][d][q]
    float* expP  = ws + 524288;       // [4][512][256]  e^{2*projP}, [b][p][d]
    float* ebuf  = ws + 1048576;      // [4][512][512]
    float* lpart = ws + 2097152;      // [4][16][512]

    proj_exp_kernel<<<dim3(512), 256, 0, stream>>>(q, p, W0, W1, expQ, expP);
    score_kernel<<<dim3(8, 16, NB), 512, 0, stream>>>(expP, expQ, vc, ebuf, lpart);
    out_kernel<<<dim3(8, 16, NB), 512, 0, stream>>>(ebuf, q, lpart, out);
}

// Round 11
// 122.188 us; speedup vs baseline: 1.0870x; 1.0870x over previous
//
#include <hip/hip_runtime.h>

#define NB 4
#define TT 512          // TQ = TP
#define DD 256
#define K2L2E    2.885390081777927f     // 2*log2(e): e^{2x} = 2^{K*x}
#define NEG2L2E (-2.885390081777927f)

#if defined(__has_builtin)
# if __has_builtin(__builtin_amdgcn_global_load_lds)
#  define HAS_GLL 1
# endif
#endif

typedef float v2f __attribute__((ext_vector_type(2)));

__device__ __forceinline__ v2f pk_fma(v2f a, v2f b, v2f c) {
#if defined(__has_builtin)
# if __has_builtin(__builtin_elementwise_fma)
    return __builtin_elementwise_fma(a, b, c);
# else
    v2f r; r.x = __builtin_fmaf(a.x, b.x, c.x); r.y = __builtin_fmaf(a.y, b.y, c.y); return r;
# endif
#else
    v2f r; r.x = __builtin_fmaf(a.x, b.x, c.x); r.y = __builtin_fmaf(a.y, b.y, c.y); return r;
#endif
}
__device__ __forceinline__ v2f splat2(float s) { v2f r; r.x = s; r.y = s; return r; }

__device__ __forceinline__ void stage16(const float* __restrict__ g, float* l) {
#ifdef HAS_GLL
    __builtin_amdgcn_global_load_lds((const __attribute__((address_space(1))) void*)g,
                                     (__attribute__((address_space(3))) void*)l, 16, 0, 0);
#else
    *(float4*)l = *(const float4*)g;
#endif
}

// ============ P1: projections + exp epilogue (v4) ============
// expQ[b][d][q] = e^{2*(q@W0)[q,d]}  (TRANSPOSED, q-minor)
// expP[b][p][d] = e^{2*(p@W1)[p,d]}  (NATURAL, d-minor)
// 256 blocks (wh x 128), 256 thr, 64m x 64n tile, 4x4 microtile (2 B/MAC),
// K-chunk 64 (4 chunks, 8 barriers), async B staging, A transpose-staged.
__global__ __launch_bounds__(256) void proj_exp_kernel(
    const float* __restrict__ qin, const float* __restrict__ pin,
    const float* __restrict__ W0, const float* __restrict__ W1,
    float* __restrict__ expQ, float* __restrict__ expP)
{
    const int blk = blockIdx.x;
    const int wh  = blk >> 7, tid = blk & 127;
    const int m0 = (tid >> 2) * 64, n0 = (tid & 3) * 64;   // m over 2048, n over 256
    const float* A = wh ? pin : qin;
    const float* W = wh ? W1 : W0;

    __shared__ __align__(16) float As[64 * 68];   // [k][m], stride 68 (272B, 16B-aligned)
    __shared__ __align__(16) float Bs[64 * 64];   // [k][n], async staged (no pad)

    const int t  = threadIdx.x;
    const int tm = t & 15, tn = t >> 4;           // microtile: m = 4*tm+i, n = 4*tn+j

    v2f acc[4][2];
    #pragma unroll
    for (int i = 0; i < 4; ++i) { acc[i][0] = splat2(0.f); acc[i][1] = splat2(0.f); }

    for (int c = 0; c < 4; ++c) {
        const int k0 = c * 64;
        // B async: 64k x 64n = 4096 f = 4 f4/thread, layout [k][64n]
        #pragma unroll
        for (int s = 0; s < 4; ++s) {
            int f = t + 256 * s, kr = f >> 4, c4 = (f & 15) * 4;
            stage16(W + (long)(k0 + kr) * DD + n0 + c4, &Bs[f * 4]);
        }
        // A manual transpose: read [m][k] f4 coalesced, write [k][m] stride 68
        #pragma unroll
        for (int s = 0; s < 4; ++s) {
            int f = t + 256 * s, mr = f >> 4, c4 = (f & 15) * 4;
            float4 a = *(const float4*)(A + (long)(m0 + mr) * DD + k0 + c4);
            As[(c4 + 0) * 68 + mr] = a.x;
            As[(c4 + 1) * 68 + mr] = a.y;
            As[(c4 + 2) * 68 + mr] = a.z;
            As[(c4 + 3) * 68 + mr] = a.w;
        }
        __syncthreads();   // drains async B + manual A
        #pragma unroll
        for (int kk = 0; kk < 64; ++kk) {
            float4 a = *(const float4*)&As[kk * 68 + 4 * tm];
            float4 b = *(const float4*)&Bs[kk * 64 + 4 * tn];
            v2f b01; b01.x = b.x; b01.y = b.y;
            v2f b23; b23.x = b.z; b23.y = b.w;
            acc[0][0] = pk_fma(splat2(a.x), b01, acc[0][0]);
            acc[0][1] = pk_fma(splat2(a.x), b23, acc[0][1]);
            acc[1][0] = pk_fma(splat2(a.y), b01, acc[1][0]);
            acc[1][1] = pk_fma(splat2(a.y), b23, acc[1][1]);
            acc[2][0] = pk_fma(splat2(a.z), b01, acc[2][0]);
            acc[2][1] = pk_fma(splat2(a.z), b23, acc[2][1]);
            acc[3][0] = pk_fma(splat2(a.w), b01, acc[3][0]);
            acc[3][1] = pk_fma(splat2(a.w), b23, acc[3][1]);
        }
        __syncthreads();   // tile consumed before next staging
    }

    const int bi = m0 >> 9;
    const int ml = m0 & 511;
    if (wh) {
        // expP natural [p][d]: per i, float4 over j; consecutive tn -> 16B coalesced
        #pragma unroll
        for (int i = 0; i < 4; ++i) {
            float4 st;
            st.x = __builtin_amdgcn_exp2f(acc[i][0].x * K2L2E);
            st.y = __builtin_amdgcn_exp2f(acc[i][0].y * K2L2E);
            st.z = __builtin_amdgcn_exp2f(acc[i][1].x * K2L2E);
            st.w = __builtin_amdgcn_exp2f(acc[i][1].y * K2L2E);
            *(float4*)(expP + ((long)bi * TT + ml + 4 * tm + i) * DD + n0 + 4 * tn) = st;
        }
    } else {
        // expQ transposed [d][q]: per j, float4 over i; consecutive tm -> 16B coalesced
        #pragma unroll
        for (int j = 0; j < 4; ++j) {
            float aj[4];
            aj[0] = (j < 2) ? ((j & 1) ? acc[0][0].y : acc[0][0].x) : ((j & 1) ? acc[0][1].y : acc[0][1].x);
            aj[1] = (j < 2) ? ((j & 1) ? acc[1][0].y : acc[1][0].x) : ((j & 1) ? acc[1][1].y : acc[1][1].x);
            aj[2] = (j < 2) ? ((j & 1) ? acc[2][0].y : acc[2][0].x) : ((j & 1) ? acc[2][1].y : acc[2][1].x);
            aj[3] = (j < 2) ? ((j & 1) ? acc[3][0].y : acc[3][0].x) : ((j & 1) ? acc[3][1].y : acc[3][1].x);
            float4 st;
            st.x = __builtin_amdgcn_exp2f(aj[0] * K2L2E);
            st.y = __builtin_amdgcn_exp2f(aj[1] * K2L2E);
            st.z = __builtin_amdgcn_exp2f(aj[2] * K2L2E);
            st.w = __builtin_amdgcn_exp2f(aj[3] * K2L2E);
            int d = n0 + 4 * tn + j;
            *(float4*)(expQ + ((long)bi * DD + d) * TT + ml + 4 * tm) = st;
        }
    }
}

// ============ P2: scores ============ (R8 exact)
__global__ __launch_bounds__(512, 6) void score_kernel(
    const float* __restrict__ expP, const float* __restrict__ expQ,
    const float* __restrict__ vc, float* __restrict__ ebuf, float* __restrict__ lpart)
{
    const int b = blockIdx.z, pt = blockIdx.y, qt = blockIdx.x;
    const int p0 = pt * 32, q0 = qt * 64;
    const int t  = threadIdx.x;
    const int qx = t & 31, py = t >> 5;

    __shared__ __align__(16) float PA[32 * 128];   // [p][d-chunk] 16 KB
    __shared__ __align__(16) float QB[128 * 64];   // [d][q] 32 KB
    __shared__ __align__(16) float vcs[DD];

    const float* gP = expP + ((long)b * TT + p0) * DD;
    const float* gQ = expQ + (long)b * DD * TT + q0;

    #pragma unroll
    for (int s = 0; s < 2; ++s) {
        int f = t + 512 * s, pr = f >> 5, d4 = (f & 31) * 4;
        stage16(gP + (long)pr * DD + d4, &PA[f * 4]);
    }
    #pragma unroll
    for (int s = 0; s < 4; ++s) {
        int f = t + 512 * s, d = f >> 4, o4 = (f & 15) * 4;
        stage16(gQ + (long)d * TT + o4, &QB[f * 4]);
    }
    if (t < DD) vcs[t] = vc[t];
    __syncthreads();

    v2f acc[2]; acc[0] = splat2(0.f); acc[1] = splat2(0.f);
    const v2f one = splat2(1.0f);

    for (int c = 0; c < 2; ++c) {
        if (c == 1) {
            __syncthreads();
            #pragma unroll
            for (int s = 0; s < 2; ++s) {
                int f = t + 512 * s, pr = f >> 5, d4 = (f & 31) * 4;
                stage16(gP + (long)pr * DD + 128 + d4, &PA[f * 4]);
            }
            #pragma unroll
            for (int s = 0; s < 4; ++s) {
                int f = t + 512 * s, d = f >> 4, o4 = (f & 15) * 4;
                stage16(gQ + (long)(128 + d) * TT + o4, &QB[f * 4]);
            }
            __syncthreads();
        }
        const float* vcb = &vcs[c * 128];
        #pragma unroll 4
        for (int dq = 0; dq < 32; ++dq) {
            float4 vq = *(const float4*)&vcb[4 * dq];
            float4 aq0 = *(const float4*)&PA[(2 * py) * 128 + 4 * dq];
            float4 aq1 = *(const float4*)&PA[(2 * py + 1) * 128 + 4 * dq];
            v2f B0 = *(const v2f*)&QB[(4 * dq + 0) * 64 + 2 * qx];
            v2f B1 = *(const v2f*)&QB[(4 * dq + 1) * 64 + 2 * qx];
            v2f B2 = *(const v2f*)&QB[(4 * dq + 2) * 64 + 2 * qx];
            v2f B3 = *(const v2f*)&QB[(4 * dq + 3) * 64 + 2 * qx];
            #pragma unroll
            for (int i = 0; i < 2; ++i) {
                float4 a = i ? aq1 : aq0;
                v2f f0 = pk_fma(splat2(a.x), B0, one);
                v2f f1 = pk_fma(splat2(a.y), B1, one);
                v2f f2 = pk_fma(splat2(a.z), B2, one);
                v2f f3 = pk_fma(splat2(a.w), B3, one);
                v2f t01 = f0 * f1;
                v2f t23 = f2 * f3;
                v2f den = t01 * t23;
                v2f n01 = pk_fma(splat2(vq.x), f1, splat2(vq.y) * f0);
                v2f n23 = pk_fma(splat2(vq.z), f3, splat2(vq.w) * f2);
                v2f num = pk_fma(n01, t23, n23 * t01);
                v2f r;
                r.x = __builtin_amdgcn_rcpf(den.x);
                r.y = __builtin_amdgcn_rcpf(den.y);
                acc[i] = pk_fma(num, r, acc[i]);
            }
        }
    }

    float* eb = ebuf + ((long)b * TT + p0) * TT + q0;
    v2f colp = splat2(0.f);
    #pragma unroll
    for (int i = 0; i < 2; ++i) {
        float2 ev;
        ev.x = __builtin_amdgcn_exp2f(acc[i].x * NEG2L2E);
        ev.y = __builtin_amdgcn_exp2f(acc[i].y * NEG2L2E);
        *(float2*)(eb + (long)(2 * py + i) * TT + 2 * qx) = ev;
        colp.x += ev.x; colp.y += ev.y;
    }
    __syncthreads();
    float* scr = (float*)&PA[0];
    *(float2*)&scr[py * 64 + 2 * qx] = make_float2(colp.x, colp.y);
    __syncthreads();
    if (t < 64) {
        float s = 0.f;
        #pragma unroll
        for (int r = 0; r < 16; ++r) s += scr[r * 64 + t];
        lpart[((long)b * 16 + pt) * TT + q0 + t] = s;
    }
}

// ============ P3: out ============ (R8 exact: 256 thr, 4-wave k-split)
__global__ __launch_bounds__(256) void out_kernel(
    const float* __restrict__ ebuf, const float* __restrict__ qin,
    const float* __restrict__ lpart, float* __restrict__ out)
{
    const int b = blockIdx.z, pt = blockIdx.y, dt = blockIdx.x;
    const int m0 = pt * 32, n0 = dt * 32;
    const int t    = threadIdx.x;       // 0..255
    const int wv   = t >> 6;            // wave 0..3 -> kk quarter
    const int lane = t & 63;
    const int pg   = lane >> 3;         // p = 4*pg + i
    const int dg   = lane & 7;          // d = 4*dg + j

    __shared__ __align__(16) float smem[4 * 32 * 36];   // staging 4352 f / reduce 4608 f
    __shared__ float linv[TT];
    float* As = smem;                    // [64k][36] transposed, linv-scaled
    float* Bs = smem + 64 * 36;          // [64k][32d]

    #pragma unroll
    for (int s = 0; s < 2; ++s) {
        int qq = t + 256 * s;
        float sum = 0.f;
        #pragma unroll
        for (int pb = 0; pb < 16; ++pb) sum += lpart[((long)b * 16 + pb) * TT + qq];
        linv[qq] = __builtin_amdgcn_rcpf(sum);
    }
    __syncthreads();

    const float* Ab = ebuf + ((long)b * TT + m0) * TT;   // 32 p-rows x 512 k
    const float* Bb = qin + (long)b * TT * DD + n0;      // 512 k-rows x 32 d

    const int ar = t >> 3, ak4 = (t & 7) * 4;            // A: p-row ar, k-quads ak4, ak4+32

    v2f acc[4][2];
    #pragma unroll
    for (int i = 0; i < 4; ++i) { acc[i][0] = splat2(0.f); acc[i][1] = splat2(0.f); }

    for (int c = 0; c < 8; ++c) {
        const int k0 = c * 64;
        #pragma unroll
        for (int s = 0; s < 2; ++s) {
            int f = t + 256 * s, kr = f >> 3, d4 = (f & 7) * 4;
            stage16(Bb + (long)(k0 + kr) * DD + d4, &Bs[f * 4]);
        }
        #pragma unroll
        for (int s = 0; s < 2; ++s) {
            int kq = ak4 + 32 * s;
            float4 a = *(const float4*)(Ab + (long)ar * TT + k0 + kq);
            float4 lv = *(const float4*)&linv[k0 + kq];
            As[(kq + 0) * 36 + ar] = a.x * lv.x;
            As[(kq + 1) * 36 + ar] = a.y * lv.y;
            As[(kq + 2) * 36 + ar] = a.z * lv.z;
            As[(kq + 3) * 36 + ar] = a.w * lv.w;
        }
        __syncthreads();
        const int kb = 16 * wv;
        #pragma unroll
        for (int u = 0; u < 16; ++u) {
            int kk = kb + u;
            float4 a  = *(const float4*)&As[kk * 36 + 4 * pg];
            float4 bq = *(const float4*)&Bs[kk * 32 + 4 * dg];
            v2f b0; b0.x = bq.x; b0.y = bq.y;
            v2f b1; b1.x = bq.z; b1.y = bq.w;
            acc[0][0] = pk_fma(splat2(a.x), b0, acc[0][0]);
            acc[0][1] = pk_fma(splat2(a.x), b1, acc[0][1]);
            acc[1][0] = pk_fma(splat2(a.y), b0, acc[1][0]);
            acc[1][1] = pk_fma(splat2(a.y), b1, acc[1][1]);
            acc[2][0] = pk_fma(splat2(a.z), b0, acc[2][0]);
            acc[2][1] = pk_fma(splat2(a.z), b1, acc[2][1]);
            acc[3][0] = pk_fma(splat2(a.w), b0, acc[3][0]);
            acc[3][1] = pk_fma(splat2(a.w), b1, acc[3][1]);
        }
        __syncthreads();
    }

    float* scr = smem;
    #pragma unroll
    for (int i = 0; i < 4; ++i) {
        *(v2f*)&scr[wv * 1152 + (4 * pg + i) * 36 + 4 * dg]     = acc[i][0];
        *(v2f*)&scr[wv * 1152 + (4 * pg + i) * 36 + 4 * dg + 2] = acc[i][1];
    }
    __syncthreads();
    {
        int pr = t >> 3, d0 = (t & 7) * 4;
        float4 s0 = *(const float4*)&scr[0 * 1152 + pr * 36 + d0];
        float4 s1 = *(const float4*)&scr[1 * 1152 + pr * 36 + d0];
        float4 s2 = *(const float4*)&scr[2 * 1152 + pr * 36 + d0];
        float4 s3 = *(const float4*)&scr[3 * 1152 + pr * 36 + d0];
        float4 v;
        v.x = (s0.x + s1.x) + (s2.x + s3.x);
        v.y = (s0.y + s1.y) + (s2.y + s3.y);
        v.z = (s0.z + s1.z) + (s2.z + s3.z);
        v.w = (s0.w + s1.w) + (s2.w + s3.w);
        *(float4*)(out + ((long)b * TT + m0 + pr) * DD + n0 + d0) = v;
    }
}

extern "C" void kernel_launch(void* const* d_in, const int* in_sizes, int n_in,
                              void* d_out, int out_size, void* d_ws, size_t ws_size,
                              hipStream_t stream) {
    const float* q  = (const float*)d_in[0];
    const float* p  = (const float*)d_in[1];
    const float* W0 = (const float*)d_in[2];
    const float* W1 = (const float*)d_in[3];
    const float* vc = (const float*)d_in[4];
    float* out = (float*)d_out;

    float* ws    = (float*)d_ws;
    float* expQ  = ws;                // [4][256][512]  e^{2*projQ}, [b][d][q]
    float* expP  = ws + 524288;       // [4][512][256]  e^{2*projP}, [b][p][d]
    float* ebuf  = ws + 1048576;      // [4][512][512]
    float* lpart = ws + 2097152;      // [4][16][512]

    proj_exp_kernel<<<dim3(256), 256, 0, stream>>>(q, p, W0, W1, expQ, expP);
    score_kernel<<<dim3(8, 16, NB), 512, 0, stream>>>(expP, expQ, vc, ebuf, lpart);
    out_kernel<<<dim3(8, 16, NB), 256, 0, stream>>>(ebuf, q, lpart, out);
}

// Round 13
// 118.727 us; speedup vs baseline: 1.1187x; 1.0292x over previous
//
#include <hip/hip_runtime.h>

#define NB 4
#define TT 512          // TQ = TP
#define DD 256
#define K2L2E    2.885390081777927f     // 2*log2(e): e^{2x} = 2^{K*x}
#define NEG2L2E (-2.885390081777927f)

#if defined(__has_builtin)
# if __has_builtin(__builtin_amdgcn_global_load_lds)
#  define HAS_GLL 1
# endif
#endif

typedef float v2f __attribute__((ext_vector_type(2)));

__device__ __forceinline__ v2f pk_fma(v2f a, v2f b, v2f c) {
#if defined(__has_builtin)
# if __has_builtin(__builtin_elementwise_fma)
    return __builtin_elementwise_fma(a, b, c);
# else
    v2f r; r.x = __builtin_fmaf(a.x, b.x, c.x); r.y = __builtin_fmaf(a.y, b.y, c.y); return r;
# endif
#else
    v2f r; r.x = __builtin_fmaf(a.x, b.x, c.x); r.y = __builtin_fmaf(a.y, b.y, c.y); return r;
#endif
}
__device__ __forceinline__ v2f splat2(float s) { v2f r; r.x = s; r.y = s; return r; }

__device__ __forceinline__ void stage16(const float* __restrict__ g, float* l) {
#ifdef HAS_GLL
    __builtin_amdgcn_global_load_lds((const __attribute__((address_space(1))) void*)g,
                                     (__attribute__((address_space(3))) void*)l, 16, 0, 0);
#else
    *(float4*)l = *(const float4*)g;
#endif
}

// ============ P1: projections + exp epilogue ============
// expQ[b][d][q] = e^{2*(q@W0)[q,d]}  (TRANSPOSED, q-minor)
// expP[b][p][d] = e^{2*(p@W1)[p,d]}  (NATURAL, d-minor)
__global__ __launch_bounds__(256) void proj_exp_kernel(
    const float* __restrict__ qin, const float* __restrict__ pin,
    const float* __restrict__ W0, const float* __restrict__ W1,
    float* __restrict__ expQ, float* __restrict__ expP)
{
    const int blk = blockIdx.x;
    const int wh = blk >> 8, tid = blk & 255;
    const int m0 = (tid >> 2) * 32, n0 = (tid & 3) * 64;
    const float* A = wh ? pin : qin;
    const float* W = wh ? W1 : W0;

    __shared__ __align__(16) float As[32 * 34];   // [k][m]
    __shared__ __align__(16) float Bs[32 * 64];   // [k][n]

    const int t  = threadIdx.x;
    const int ar = t >> 3, ac4 = (t & 7) * 4;
    const int br = t >> 4, bc4 = (t & 15) * 4;
    const int tm = wh ? (t >> 4) : (t & 15);
    const int tn = wh ? (t & 15) : (t >> 4);

    const float* Ap = A + (long)(m0 + ar) * DD + ac4;

    float4 av  = *(const float4*)Ap;
    float4 bv0 = *(const float4*)(W + (long)br * DD + n0 + bc4);
    float4 bv1 = *(const float4*)(W + (long)(br + 16) * DD + n0 + bc4);

    v2f accv[2][2];
    accv[0][0] = splat2(0.f); accv[0][1] = splat2(0.f);
    accv[1][0] = splat2(0.f); accv[1][1] = splat2(0.f);

    for (int c = 0; c < 8; ++c) {
        As[(ac4 + 0) * 34 + ar] = av.x;
        As[(ac4 + 1) * 34 + ar] = av.y;
        As[(ac4 + 2) * 34 + ar] = av.z;
        As[(ac4 + 3) * 34 + ar] = av.w;
        *(float4*)&Bs[br * 64 + bc4]        = bv0;
        *(float4*)&Bs[(br + 16) * 64 + bc4] = bv1;
        __syncthreads();
        if (c < 7) {
            int k1 = (c + 1) * 32;
            av  = *(const float4*)(Ap + k1);
            bv0 = *(const float4*)(W + (long)(k1 + br) * DD + n0 + bc4);
            bv1 = *(const float4*)(W + (long)(k1 + 16 + br) * DD + n0 + bc4);
        }
        #pragma unroll
        for (int kk = 0; kk < 32; ++kk) {
            float2 a = *(const float2*)&As[kk * 34 + 2 * tm];
            float4 b = *(const float4*)&Bs[kk * 64 + 4 * tn];
            v2f b01; b01.x = b.x; b01.y = b.y;
            v2f b23; b23.x = b.z; b23.y = b.w;
            accv[0][0] = pk_fma(splat2(a.x), b01, accv[0][0]);
            accv[0][1] = pk_fma(splat2(a.x), b23, accv[0][1]);
            accv[1][0] = pk_fma(splat2(a.y), b01, accv[1][0]);
            accv[1][1] = pk_fma(splat2(a.y), b23, accv[1][1]);
        }
        __syncthreads();
    }

    float acc[2][4];
    #pragma unroll
    for (int i = 0; i < 2; ++i) {
        acc[i][0] = accv[i][0].x; acc[i][1] = accv[i][0].y;
        acc[i][2] = accv[i][1].x; acc[i][3] = accv[i][1].y;
    }

    const int bi = m0 >> 9;
    const int ml = m0 & 511;
    if (wh) {
        #pragma unroll
        for (int i = 0; i < 2; ++i) {
            float4 st;
            st.x = __builtin_amdgcn_exp2f(acc[i][0] * K2L2E);
            st.y = __builtin_amdgcn_exp2f(acc[i][1] * K2L2E);
            st.z = __builtin_amdgcn_exp2f(acc[i][2] * K2L2E);
            st.w = __builtin_amdgcn_exp2f(acc[i][3] * K2L2E);
            *(float4*)(expP + ((long)bi * TT + ml + 2 * tm + i) * DD + n0 + 4 * tn) = st;
        }
    } else {
        #pragma unroll
        for (int j = 0; j < 4; ++j) {
            int d = n0 + 4 * tn + j;
            float2 st;
            st.x = __builtin_amdgcn_exp2f(acc[0][j] * K2L2E);
            st.y = __builtin_amdgcn_exp2f(acc[1][j] * K2L2E);
            *(float2*)(expQ + ((long)bi * DD + d) * TT + ml + 2 * tm) = st;
        }
    }
}

// ============ P2: scores ============
// 32p x 64q tile, 512 thr, 2p x 2q-pk microtile, d-quad rcp batching with
// fused f = 1+E = pk_fma(a, B, 1):
//   sum v_k/f_k = (n01*t23 + n23*t01) * rcp(t01*t23),  n01 = v0*f1 + v1*f0
// 14 pk + 2 rcp per (i, d-quad). Two 128-d chunks, no dbuf, 49.4 KB LDS.
__global__ __launch_bounds__(512, 6) void score_kernel(
    const float* __restrict__ expP, const float* __restrict__ expQ,
    const float* __restrict__ vc, float* __restrict__ ebuf, float* __restrict__ lpart)
{
    const int b = blockIdx.z, pt = blockIdx.y, qt = blockIdx.x;
    const int p0 = pt * 32, q0 = qt * 64;
    const int t  = threadIdx.x;
    const int qx = t & 31, py = t >> 5;

    __shared__ __align__(16) float PA[32 * 128];   // [p][d-chunk] 16 KB
    __shared__ __align__(16) float QB[128 * 64];   // [d][q] 32 KB
    __shared__ __align__(16) float vcs[DD];

    const float* gP = expP + ((long)b * TT + p0) * DD;
    const float* gQ = expQ + (long)b * DD * TT + q0;

    #pragma unroll
    for (int s = 0; s < 2; ++s) {
        int f = t + 512 * s, pr = f >> 5, d4 = (f & 31) * 4;
        stage16(gP + (long)pr * DD + d4, &PA[f * 4]);
    }
    #pragma unroll
    for (int s = 0; s < 4; ++s) {
        int f = t + 512 * s, d = f >> 4, o4 = (f & 15) * 4;
        stage16(gQ + (long)d * TT + o4, &QB[f * 4]);
    }
    if (t < DD) vcs[t] = vc[t];
    __syncthreads();

    v2f acc[2]; acc[0] = splat2(0.f); acc[1] = splat2(0.f);
    const v2f one = splat2(1.0f);

    for (int c = 0; c < 2; ++c) {
        if (c == 1) {
            __syncthreads();
            #pragma unroll
            for (int s = 0; s < 2; ++s) {
                int f = t + 512 * s, pr = f >> 5, d4 = (f & 31) * 4;
                stage16(gP + (long)pr * DD + 128 + d4, &PA[f * 4]);
            }
            #pragma unroll
            for (int s = 0; s < 4; ++s) {
                int f = t + 512 * s, d = f >> 4, o4 = (f & 15) * 4;
                stage16(gQ + (long)(128 + d) * TT + o4, &QB[f * 4]);
            }
            __syncthreads();
        }
        const float* vcb = &vcs[c * 128];
        #pragma unroll 4
        for (int dq = 0; dq < 32; ++dq) {
            float4 vq = *(const float4*)&vcb[4 * dq];
            float4 aq0 = *(const float4*)&PA[(2 * py) * 128 + 4 * dq];
            float4 aq1 = *(const float4*)&PA[(2 * py + 1) * 128 + 4 * dq];
            v2f B0 = *(const v2f*)&QB[(4 * dq + 0) * 64 + 2 * qx];
            v2f B1 = *(const v2f*)&QB[(4 * dq + 1) * 64 + 2 * qx];
            v2f B2 = *(const v2f*)&QB[(4 * dq + 2) * 64 + 2 * qx];
            v2f B3 = *(const v2f*)&QB[(4 * dq + 3) * 64 + 2 * qx];
            #pragma unroll
            for (int i = 0; i < 2; ++i) {
                float4 a = i ? aq1 : aq0;
                v2f f0 = pk_fma(splat2(a.x), B0, one);
                v2f f1 = pk_fma(splat2(a.y), B1, one);
                v2f f2 = pk_fma(splat2(a.z), B2, one);
                v2f f3 = pk_fma(splat2(a.w), B3, one);
                v2f t01 = f0 * f1;
                v2f t23 = f2 * f3;
                v2f den = t01 * t23;
                v2f n01 = pk_fma(splat2(vq.x), f1, splat2(vq.y) * f0);
                v2f n23 = pk_fma(splat2(vq.z), f3, splat2(vq.w) * f2);
                v2f num = pk_fma(n01, t23, n23 * t01);
                v2f r;
                r.x = __builtin_amdgcn_rcpf(den.x);
                r.y = __builtin_amdgcn_rcpf(den.y);
                acc[i] = pk_fma(num, r, acc[i]);
            }
        }
    }

    float* eb = ebuf + ((long)b * TT + p0) * TT + q0;
    v2f colp = splat2(0.f);
    #pragma unroll
    for (int i = 0; i < 2; ++i) {
        float2 ev;
        ev.x = __builtin_amdgcn_exp2f(acc[i].x * NEG2L2E);
        ev.y = __builtin_amdgcn_exp2f(acc[i].y * NEG2L2E);
        *(float2*)(eb + (long)(2 * py + i) * TT + 2 * qx) = ev;
        colp.x += ev.x; colp.y += ev.y;
    }
    __syncthreads();
    float* scr = (float*)&PA[0];
    *(float2*)&scr[py * 64 + 2 * qx] = make_float2(colp.x, colp.y);
    __syncthreads();
    if (t < 64) {
        float s = 0.f;
        #pragma unroll
        for (int r = 0; r < 16; ++r) s += scr[r * 64 + t];
        lpart[((long)b * 16 + pt) * TT + q0 + t] = s;
    }
}

// ============ P3: out[b,p,:] = sum_q (e[p,q]/l[q]) * qin[b,q,:] ============
// 32p x 32d tile, 256 thr (4 waves), 4p x 4d per-lane microtile; each wave
// owns a 16-kk quarter of every 64-k chunk (k-split), LDS reduce at end.
// B staged async [k][d]; A transpose-staged with linv[k] folded in.
__global__ __launch_bounds__(256) void out_kernel(
    const float* __restrict__ ebuf, const float* __restrict__ qin,
    const float* __restrict__ lpart, float* __restrict__ out)
{
    const int b = blockIdx.z, pt = blockIdx.y, dt = blockIdx.x;
    const int m0 = pt * 32, n0 = dt * 32;
    const int t    = threadIdx.x;       // 0..255
    const int wv   = t >> 6;            // wave 0..3 -> kk quarter
    const int lane = t & 63;
    const int pg   = lane >> 3;         // p = 4*pg + i
    const int dg   = lane & 7;          // d = 4*dg + j

    __shared__ __align__(16) float smem[4 * 32 * 36];   // staging 4352 f / reduce 4608 f
    __shared__ float linv[TT];
    float* As = smem;                    // [64k][36] transposed, linv-scaled
    float* Bs = smem + 64 * 36;          // [64k][32d]

    #pragma unroll
    for (int s = 0; s < 2; ++s) {
        int qq = t + 256 * s;
        float sum = 0.f;
        #pragma unroll
        for (int pb = 0; pb < 16; ++pb) sum += lpart[((long)b * 16 + pb) * TT + qq];
        linv[qq] = __builtin_amdgcn_rcpf(sum);
    }
    __syncthreads();

    const float* Ab = ebuf + ((long)b * TT + m0) * TT;   // 32 p-rows x 512 k
    const float* Bb = qin + (long)b * TT * DD + n0;      // 512 k-rows x 32 d

    const int ar = t >> 3, ak4 = (t & 7) * 4;            // A: p-row ar, k-quads ak4, ak4+32

    v2f acc[4][2];
    #pragma unroll
    for (int i = 0; i < 4; ++i) { acc[i][0] = splat2(0.f); acc[i][1] = splat2(0.f); }

    for (int c = 0; c < 8; ++c) {
        const int k0 = c * 64;
        #pragma unroll
        for (int s = 0; s < 2; ++s) {
            int f = t + 256 * s, kr = f >> 3, d4 = (f & 7) * 4;
            stage16(Bb + (long)(k0 + kr) * DD + d4, &Bs[f * 4]);
        }
        #pragma unroll
        for (int s = 0; s < 2; ++s) {
            int kq = ak4 + 32 * s;
            float4 a = *(const float4*)(Ab + (long)ar * TT + k0 + kq);
            float4 lv = *(const float4*)&linv[k0 + kq];
            As[(kq + 0) * 36 + ar] = a.x * lv.x;
            As[(kq + 1) * 36 + ar] = a.y * lv.y;
            As[(kq + 2) * 36 + ar] = a.z * lv.z;
            As[(kq + 3) * 36 + ar] = a.w * lv.w;
        }
        __syncthreads();
        const int kb = 16 * wv;
        #pragma unroll
        for (int u = 0; u < 16; ++u) {
            int kk = kb + u;
            float4 a  = *(const float4*)&As[kk * 36 + 4 * pg];
            float4 bq = *(const float4*)&Bs[kk * 32 + 4 * dg];
            v2f b0; b0.x = bq.x; b0.y = bq.y;
            v2f b1; b1.x = bq.z; b1.y = bq.w;
            acc[0][0] = pk_fma(splat2(a.x), b0, acc[0][0]);
            acc[0][1] = pk_fma(splat2(a.x), b1, acc[0][1]);
            acc[1][0] = pk_fma(splat2(a.y), b0, acc[1][0]);
            acc[1][1] = pk_fma(splat2(a.y), b1, acc[1][1]);
            acc[2][0] = pk_fma(splat2(a.z), b0, acc[2][0]);
            acc[2][1] = pk_fma(splat2(a.z), b1, acc[2][1]);
            acc[3][0] = pk_fma(splat2(a.w), b0, acc[3][0]);
            acc[3][1] = pk_fma(splat2(a.w), b1, acc[3][1]);
        }
        __syncthreads();
    }

    float* scr = smem;
    #pragma unroll
    for (int i = 0; i < 4; ++i) {
        *(v2f*)&scr[wv * 1152 + (4 * pg + i) * 36 + 4 * dg]     = acc[i][0];
        *(v2f*)&scr[wv * 1152 + (4 * pg + i) * 36 + 4 * dg + 2] = acc[i][1];
    }
    __syncthreads();
    {
        int pr = t >> 3, d0 = (t & 7) * 4;
        float4 s0 = *(const float4*)&scr[0 * 1152 + pr * 36 + d0];
        float4 s1 = *(const float4*)&scr[1 * 1152 + pr * 36 + d0];
        float4 s2 = *(const float4*)&scr[2 * 1152 + pr * 36 + d0];
        float4 s3 = *(const float4*)&scr[3 * 1152 + pr * 36 + d0];
        float4 v;
        v.x = (s0.x + s1.x) + (s2.x + s3.x);
        v.y = (s0.y + s1.y) + (s2.y + s3.y);
        v.z = (s0.z + s1.z) + (s2.z + s3.z);
        v.w = (s0.w + s1.w) + (s2.w + s3.w);
        *(float4*)(out + ((long)b * TT + m0 + pr) * DD + n0 + d0) = v;
    }
}

extern "C" void kernel_launch(void* const* d_in, const int* in_sizes, int n_in,
                              void* d_out, int out_size, void* d_ws, size_t ws_size,
                              hipStream_t stream) {
    const float* q  = (const float*)d_in[0];
    const float* p  = (const float*)d_in[1];
    const float* W0 = (const float*)d_in[2];
    const float* W1 = (const float*)d_in[3];
    const float* vc = (const float*)d_in[4];
    float* out = (float*)d_out;

    float* ws    = (float*)d_ws;
    float* expQ  = ws;                // [4][256][512]  e^{2*projQ}, [b][d][q]
    float* expP  = ws + 524288;       // [4][512][256]  e^{2*projP}, [b][p][d]
    float* ebuf  = ws + 1048576;      // [4][512][512]
    float* lpart = ws + 2097152;      // [4][16][512]

    proj_exp_kernel<<<dim3(512), 256, 0, stream>>>(q, p, W0, W1, expQ, expP);
    score_kernel<<<dim3(8, 16, NB), 512, 0, stream>>>(expP, expQ, vc, ebuf, lpart);
    out_kernel<<<dim3(8, 16, NB), 256, 0, stream>>>(ebuf, q, lpart, out);
}